// Round 7
// baseline (369.125 us; speedup 1.0000x reference)
//
#include <hip/hip_runtime.h>
#include <hip/hip_bf16.h>

#define BB 8
#define TT 4
#define NN 4096
#define UU 64
#define EE 65536
#define BN (BB*NN)   // 32768
#define CAP 64
#define NEG 0.2f
#define SLP 68       // LDS row stride: 16B-aligned (68*4=272), b128-friendly

// ws layout (float offsets); hp/es/ed ping-pong by t parity
#define OFF_XT   0                      // 12*BN  (t,f,row)
#define OFF_HP0  (12*BN)                // BN*64 row-major h'
#define OFF_HP1  (OFF_HP0 + 64*BN)
#define OFF_ES0  (OFF_HP1 + 64*BN)     // BN
#define OFF_ES1  (OFF_ES0 + BN)
#define OFF_ED0  (OFF_ES1 + BN)
#define OFF_ED1  (OFF_ED0 + BN)
#define OFF_CNT  (OFF_ED1 + BN)        // NN ints
#define OFF_SLOT (OFF_CNT + NN)        // NN*CAP ints (ends ~19.9 MB)

__global__ __launch_bounds__(256) void k_conv_x(const float* x, float* xT) {
  int i = blockIdx.x * 256 + threadIdx.x;     // < 12*BN
  int r = i & (BN - 1);
  int tf = i >> 15;
  int t = tf / 3, f = tf - 3 * t;
  int b = r >> 12, n = r & (NN - 1);
  xT[i] = x[(((b * TT + t) * NN + n) * 3) + f];
}

__global__ __launch_bounds__(256) void k_fill(const int* src, const int* dst,
                                              int* cnt, int* slot) {
  int i = blockIdx.x * 256 + threadIdx.x;
  if (i < EE) {
    int d = dst[i];
    int p = atomicAdd(&cnt[d], 1);
    if (p < CAP) slot[d * CAP + p] = src[i];
  } else if (i < EE + NN) {
    int n = i - EE;
    int p = atomicAdd(&cnt[n], 1);
    if (p < CAP) slot[n * CAP + p] = n;
  }
}

// GAT at t=0 (h == 0): h' = x_0 @ gat_W[64:67]; es/ed. Writes buffer 0.
__global__ __launch_bounds__(512) void k_gat0(float* ws, const float* gW,
                                              const float* as_, const float* ad_) {
  const float* xT = ws + OFF_XT;
  float* hp = ws + OFF_HP0;
  float* es = ws + OFF_ES0;
  float* ed = ws + OFF_ED0;
  int wave = __builtin_amdgcn_readfirstlane(threadIdx.x >> 6);
  int lane = threadIdx.x & 63;
  int row = blockIdx.x * 64 + lane;
  int u0 = wave * 8;
  float acc[8];
#pragma unroll
  for (int j = 0; j < 8; ++j) acc[j] = 0.f;
#pragma unroll
  for (int k = 0; k < 3; ++k) {
    float ck = xT[k * BN + row];   // t=0
#pragma unroll
    for (int j = 0; j < 8; ++j) acc[j] += ck * gW[(64 + k) * 64 + u0 + j];
  }
  float esa = 0.f, eda = 0.f;
#pragma unroll
  for (int j = 0; j < 8; ++j) {
    esa += acc[j] * as_[u0 + j];
    eda += acc[j] * ad_[u0 + j];
  }
  float4* o = (float4*)(hp + (size_t)row * 64 + u0);
  o[0] = make_float4(acc[0], acc[1], acc[2], acc[3]);
  o[1] = make_float4(acc[4], acc[5], acc[6], acc[7]);
  __shared__ float esL[8][64], edL[8][64];
  esL[wave][lane] = esa;
  edL[wave][lane] = eda;
  __syncthreads();
  if (wave == 0) {
    float s = 0.f;
#pragma unroll
    for (int w = 0; w < 8; ++w) s += esL[w][lane];
    es[row] = s;
  } else if (wave == 1) {
    float s = 0.f;
#pragma unroll
    for (int w = 0; w < 8; ++w) s += edL[w][lane];
    ed[row] = s;
  }
}

// Fused step: attn(t) -> GRU(t) -> [GAT(t+1) | out head].
// 512 thr, 8 waves, 64 rows/block, grid = 512. GEMMs: lane = u (output col),
// weight column in VGPRs, s/rs broadcast from LDS (row-major, b128 reads).
__global__ __launch_bounds__(512, 4) void k_step(
    float* ws, const float* gb, const float* g1W, const float* g1b,
    const float* g2W, const float* g2b, const float* gW, const float* as_,
    const float* ad_, const float* oW, const float* ob, float* out, int t,
    int last) {
  const float* xT = ws + OFF_XT;
  int pr = t & 1;
  const float* hpR = ws + (pr ? OFF_HP1 : OFF_HP0);
  const float* esR = ws + (pr ? OFF_ES1 : OFF_ES0);
  const float* edR = ws + (pr ? OFF_ED1 : OFF_ED0);
  float* hpW = ws + (pr ? OFF_HP0 : OFF_HP1);
  float* esW = ws + (pr ? OFF_ES0 : OFF_ES1);
  float* edW = ws + (pr ? OFF_ED0 : OFF_ED1);
  const int* cnt = (const int*)(ws + OFF_CNT);
  const int* slot = (const int*)(ws + OFF_SLOT);

  int wave = __builtin_amdgcn_readfirstlane(threadIdx.x >> 6);
  int lane = threadIdx.x & 63;
  int rowbase = blockIdx.x * 64;
  int b = rowbase / NN;
  int nbase = rowbase - b * NN;
  __shared__ float sL[64][SLP];    // [row_local][u]
  __shared__ float rsL[64][SLP];   // [row_local][u]
  __shared__ float xS[6][64];      // [t:3 | t+1:3][row_local]

  // stage x for step t (and t+1 if not last)
  if (threadIdx.x < 384) {
    int k = threadIdx.x >> 6;          // 0..5
    int r = threadIdx.x & 63;
    int tt = t + (k >= 3 ? 1 : 0);
    int f = (k >= 3) ? k - 3 : k;
    if (tt < TT) xS[k][r] = xT[(tt * 3 + f) * BN + rowbase + r];
  }

  float gbv = gb[lane];   // lane = u

  // ---- P1: attention, 8 rows per wave; write sL[row][u] ----
#pragma unroll 1
  for (int rr = 0; rr < 8; ++rr) {
    int lr = wave * 8 + rr;
    int n = nbase + lr;
    int grow = b * NN + n;
    int deg = min(cnt[n], CAP);
    float edv = edR[grow];
    int sl = (lane < deg) ? slot[n * CAP + lane] : 0;
    float e;
    if (lane < deg) {
      e = esR[b * NN + sl] + edv;
      e = e > 0.f ? e : NEG * e;
    } else {
      e = -1e30f;
    }
    float m = e;
#pragma unroll
    for (int o = 32; o >= 1; o >>= 1) m = fmaxf(m, __shfl_xor(m, o, 64));
    float w = (lane < deg) ? __expf(e - m) : 0.f;
    float dsum = w;
#pragma unroll
    for (int o = 32; o >= 1; o >>= 1) dsum += __shfl_xor(dsum, o, 64);
    w *= 1.f / dsum;
    float acc = 0.f;
#pragma unroll 1
    for (int i0 = 0; i0 < deg; i0 += 8) {
      int sis[8];
      float wv[8];
#pragma unroll
      for (int j = 0; j < 8; ++j) {
        int i = i0 + j;
        sis[j] = __shfl(sl, i, 64);
        float t_ = __shfl(w, i, 64);
        wv[j] = (i < deg) ? t_ : 0.f;
      }
      float v[8];
#pragma unroll
      for (int j = 0; j < 8; ++j)
        v[j] = hpR[(size_t)(b * NN + sis[j]) * 64 + lane];
#pragma unroll
      for (int j = 0; j < 8; ++j) acc += wv[j] * v[j];
    }
    sL[lr][lane] = acc + gbv;
  }
  __syncthreads();

  int r0 = wave * 8;
  float w[67];
  float acc[8];

  // ---- P2: r gate; w = g1W[:, lane] (r half) ----
#pragma unroll
  for (int k = 0; k < 67; ++k) w[k] = g1W[k * 128 + lane];
#pragma unroll
  for (int r = 0; r < 8; ++r) {
    int lr = r0 + r;
    float a = xS[0][lr] * w[0] + xS[1][lr] * w[1] + xS[2][lr] * w[2];
    const float4* s4 = (const float4*)&sL[lr][0];
#pragma unroll
    for (int q = 0; q < 16; ++q) {
      float4 sv = s4[q];
      a += sv.x * w[3 + 4 * q] + sv.y * w[4 + 4 * q] + sv.z * w[5 + 4 * q] +
           sv.w * w[6 + 4 * q];
    }
    acc[r] = a;
  }
  float g1bv = g1b[lane];
#pragma unroll
  for (int r = 0; r < 8; ++r) {
    int lr = r0 + r;
    float rg = 1.f / (1.f + __expf(-(acc[r] + g1bv)));
    rsL[lr][lane] = rg * sL[lr][lane];
  }
  __syncthreads();

  // ---- P3a: u gate; w = g1W[:, 64+lane] ----
#pragma unroll
  for (int k = 0; k < 67; ++k) w[k] = g1W[k * 128 + 64 + lane];
#pragma unroll
  for (int r = 0; r < 8; ++r) {
    int lr = r0 + r;
    float a = xS[0][lr] * w[0] + xS[1][lr] * w[1] + xS[2][lr] * w[2];
    const float4* s4 = (const float4*)&sL[lr][0];
#pragma unroll
    for (int q = 0; q < 16; ++q) {
      float4 sv = s4[q];
      a += sv.x * w[3 + 4 * q] + sv.y * w[4 + 4 * q] + sv.z * w[5 + 4 * q] +
           sv.w * w[6 + 4 * q];
    }
    acc[r] = a;
  }
  float g1bu = g1b[64 + lane];
  float ug[8];
#pragma unroll
  for (int r = 0; r < 8; ++r) ug[r] = 1.f / (1.f + __expf(-(acc[r] + g1bu)));

  // ---- P3b: candidate on rs; w = g2W[:, lane]; then h ----
#pragma unroll
  for (int k = 0; k < 67; ++k) w[k] = g2W[k * 64 + lane];
#pragma unroll
  for (int r = 0; r < 8; ++r) {
    int lr = r0 + r;
    float a = xS[0][lr] * w[0] + xS[1][lr] * w[1] + xS[2][lr] * w[2];
    const float4* s4 = (const float4*)&rsL[lr][0];
#pragma unroll
    for (int q = 0; q < 16; ++q) {
      float4 sv = s4[q];
      a += sv.x * w[3 + 4 * q] + sv.y * w[4 + 4 * q] + sv.z * w[5 + 4 * q] +
           sv.w * w[6 + 4 * q];
    }
    acc[r] = a;
  }
  float g2bv = g2b[lane];
  float h[8];
#pragma unroll
  for (int r = 0; r < 8; ++r) {
    int lr = r0 + r;
    float z = acc[r] + g2bv;
    float c = 1.f - 2.f / (__expf(2.f * z) + 1.f);
    h[r] = ug[r] * sL[lr][lane] + (1.f - ug[r]) * c;
  }
  __syncthreads();
#pragma unroll
  for (int r = 0; r < 8; ++r) sL[r0 + r][lane] = h[r];
  __syncthreads();

  if (!last) {
    // ---- P5: GAT(t+1); w = gat_W[:, lane] (rows 0..63 = h, 64..66 = x) ----
#pragma unroll
    for (int k = 0; k < 67; ++k) w[k] = gW[k * 64 + lane];
    float asv = as_[lane], adv = ad_[lane];
#pragma unroll 1
    for (int r = 0; r < 8; ++r) {
      int lr = r0 + r;
      const float4* s4 = (const float4*)&sL[lr][0];
      float a = xS[3][lr] * w[64] + xS[4][lr] * w[65] + xS[5][lr] * w[66];
#pragma unroll
      for (int q = 0; q < 16; ++q) {
        float4 sv = s4[q];
        a += sv.x * w[4 * q] + sv.y * w[4 * q + 1] + sv.z * w[4 * q + 2] +
             sv.w * w[4 * q + 3];
      }
      hpW[(size_t)(rowbase + lr) * 64 + lane] = a;
      float pe = a * asv, pd = a * adv;
#pragma unroll
      for (int o = 32; o >= 1; o >>= 1) {
        pe += __shfl_xor(pe, o, 64);
        pd += __shfl_xor(pd, o, 64);
      }
      if (lane == 0) {
        esW[rowbase + lr] = pe;
        edW[rowbase + lr] = pd;
      }
    }
  } else {
    // ---- P5': output head out[row,:] = h . oW + ob ----
    if (wave < 3) {
      float a = ob[wave];
#pragma unroll 8
      for (int k = 0; k < 64; ++k) a += sL[lane][k] * oW[k * 3 + wave];
      out[(size_t)(rowbase + lane) * 3 + wave] = a;
    }
  }
}

extern "C" void kernel_launch(void* const* d_in, const int* in_sizes, int n_in,
                              void* d_out, int out_size, void* d_ws, size_t ws_size,
                              hipStream_t stream) {
  const float* x = (const float*)d_in[0];
  const int* src = (const int*)d_in[1];
  const int* dst = (const int*)d_in[2];
  const float* gatW = (const float*)d_in[3];
  const float* asrc = (const float*)d_in[4];
  const float* adst = (const float*)d_in[5];
  const float* gatb = (const float*)d_in[6];
  const float* g1W = (const float*)d_in[7];
  const float* g1b = (const float*)d_in[8];
  const float* g2W = (const float*)d_in[9];
  const float* g2b = (const float*)d_in[10];
  const float* oW = (const float*)d_in[11];
  const float* ob = (const float*)d_in[12];
  float* ws = (float*)d_ws;
  float* out = (float*)d_out;

  hipMemsetAsync(ws + OFF_CNT, 0, NN * sizeof(int), stream);
  k_conv_x<<<(12 * BN) / 256, 256, 0, stream>>>(x, ws + OFF_XT);
  k_fill<<<(EE + NN) / 256, 256, 0, stream>>>(src, dst, (int*)(ws + OFF_CNT),
                                              (int*)(ws + OFF_SLOT));
  k_gat0<<<BN / 64, 512, 0, stream>>>(ws, gatW, asrc, adst);
  for (int t = 0; t < TT; ++t) {
    k_step<<<BN / 64, 512, 0, stream>>>(ws, gatb, g1W, g1b, g2W, g2b, gatW,
                                        asrc, adst, oW, ob, out, t,
                                        t == TT - 1 ? 1 : 0);
  }
}